// Round 4
// baseline (321.758 us; speedup 1.0000x reference)
//
#include <hip/hip_runtime.h>
#include <hip/hip_bf16.h>
#include <stdint.h>

#define SQ 8192
#define SK 8192
#define DH 128
#define NIT 16               // iterations; per iter the 8 waves cover 256 keys (of this half)
#define L2E 1.4426950408889634f
#define CB 40.0f             // fixed log2-domain softmax offset (R7-proven)

typedef __attribute__((ext_vector_type(8))) _Float16 f16x8;
typedef __attribute__((ext_vector_type(8))) short bf16x8;
typedef __attribute__((ext_vector_type(16))) float f32x16;
typedef __attribute__((ext_vector_type(4))) short s16x4;
typedef __attribute__((ext_vector_type(4))) unsigned int u32x4;

__device__ __forceinline__ short f2h(float f) {
  _Float16 h = (_Float16)f;
  return __builtin_bit_cast(short, h);
}
__device__ __forceinline__ short f2bf(float f) {   // RNE
  uint32_t u = __builtin_bit_cast(uint32_t, f);
  u = (u + 0x7FFFu + ((u >> 16) & 1u)) >> 16;
  return (short)u;
}

// ---- prep: blocks [0,256) build K image; blocks [256,512) build V image.
// Kimg[kb][kc][lane][j] = fp16 K[kb*32 + (lane&31)][kc*16 + (lane>>5)*8 + j]
// Vimg[kb][g=ks*4+dt][lane][j] = bf16 V[key][dt*32 + (lane&31)], key axis permuted
//   to S^T C-layout order: key = kb*32 + ks*16 + (lane>>5)*4 + (j&3) + 8*(j>>2).
__global__ __launch_bounds__(256) void prep_kernel(const float* __restrict__ K,
                                                   const float* __restrict__ V,
                                                   short* __restrict__ Kimg,
                                                   short* __restrict__ Vimg) {
  __shared__ short T[32][136];
  const int tid = threadIdx.x;
  if (blockIdx.x < 256) {
    const int kb = blockIdx.x;
#pragma unroll
    for (int i = 0; i < 2; ++i) {
      int ci = i * 256 + tid;            // chunk id, 512 per kb
      int kc = ci >> 6, lane = ci & 63;
      int key = kb * 32 + (lane & 31);
      int k0 = kc * 16 + (lane >> 5) * 8;
      const float* src = K + (size_t)key * DH + k0;
      float4 a = *(const float4*)src;
      float4 b = *(const float4*)(src + 4);
      s16x4 o0, o1;
      o0.x = f2h(a.x); o0.y = f2h(a.y); o0.z = f2h(a.z); o0.w = f2h(a.w);
      o1.x = f2h(b.x); o1.y = f2h(b.y); o1.z = f2h(b.z); o1.w = f2h(b.w);
      s16x4* dst = (s16x4*)(Kimg + (size_t)kb * 4096 + ci * 8);
      dst[0] = o0; dst[1] = o1;
    }
  } else {
    const int kb = blockIdx.x - 256;
#pragma unroll
    for (int i = 0; i < 4; ++i) {
      int fi = i * 256 + tid;            // float4 id in 32x128 tile
      int key = fi >> 5;
      int dc = (fi & 31) * 4;
      float4 v = ((const float4*)V)[(size_t)(kb * 32 + key) * (DH / 4) + (fi & 31)];
      T[key][dc + 0] = f2bf(v.x); T[key][dc + 1] = f2bf(v.y);
      T[key][dc + 2] = f2bf(v.z); T[key][dc + 3] = f2bf(v.w);
    }
    __syncthreads();
#pragma unroll
    for (int i = 0; i < 2; ++i) {
      int ci = i * 256 + tid;            // chunk id, 512 per kb
      int lane = ci & 63;
      int g = ci >> 6;                   // ks*4 + dt
      int dt = g & 3, ks = g >> 2;
      int base = ks * 16 + (lane >> 5) * 4;   // permuted key base
      int d = dt * 32 + (lane & 31);
      s16x4 o0, o1;
      o0.x = T[base + 0][d]; o0.y = T[base + 1][d];
      o0.z = T[base + 2][d]; o0.w = T[base + 3][d];
      o1.x = T[base + 8][d]; o1.y = T[base + 9][d];
      o1.z = T[base + 10][d]; o1.w = T[base + 11][d];
      s16x4* dst = (s16x4*)(Vimg + (size_t)kb * 4096 + ci * 8);
      dst[0] = o0; dst[1] = o1;
    }
  }
}

// ---- main: R0-proven datapath (direct-L2 K/V, 8 independent wave stripes),
// but keys split 2-way across blocks -> grid 512 = 2 blocks/CU = 4 waves/SIMD
// (double latency hiding vs R0/R2's 2). Block (qb, kh) does 32 q-rows x 4096
// keys. XCD swizzle pins kh per XCD so each XCD's L2 holds only its 2 MB
// half-image. Max-free softmax (fixed CB) makes key-half partials additive:
// block writes unnormalized O + l; combine_kernel divides.
__global__ __launch_bounds__(512, 4) void attn_split(const float* __restrict__ Q,
                                                     const short* __restrict__ Kimg,
                                                     const short* __restrict__ Vimg,
                                                     float* __restrict__ Oa,
                                                     float* __restrict__ Ob,
                                                     float* __restrict__ l0,
                                                     float* __restrict__ l1) {
  __shared__ __align__(16) char smem[67584];   // merge only: 4 regions x 32 x 132 fp32
  const int tid = threadIdx.x;
  const int w = tid >> 6;
  const int lane = tid & 63;
  const int half = lane >> 5;
  const int l32 = lane & 31;
  // XCD-pinned decode: xcd = b&7 (round-robin dispatch); kh fixed per XCD,
  // qb = (b>>3)*4 + (b&3). Bijective over b in [0,512).
  const int b = blockIdx.x;
  const int kh = (b >> 2) & 1;
  const int qb = (b >> 3) * 4 + (b & 3);
  const int qrow0 = qb * 32;
  const int kb0 = kh * 128;            // first 32-key block of this half

  // Q B-frags fp16: qf[kc][j] = Q[qrow0 + l32][kc*16 + half*8 + j]
  f16x8 qf[8];
  {
    const float* qp = Q + (size_t)(qrow0 + l32) * DH + half * 8;
#pragma unroll
    for (int kc = 0; kc < 8; ++kc) {
      float4 a = *(const float4*)(qp + kc * 16);
      float4 b2 = *(const float4*)(qp + kc * 16 + 4);
      f16x8 h;
      h[0] = (_Float16)a.x; h[1] = (_Float16)a.y; h[2] = (_Float16)a.z; h[3] = (_Float16)a.w;
      h[4] = (_Float16)b2.x; h[5] = (_Float16)b2.y; h[6] = (_Float16)b2.z; h[7] = (_Float16)b2.w;
      qf[kc] = h;
    }
  }

  f32x16 of[4];
#pragma unroll
  for (int dt = 0; dt < 4; ++dt)
#pragma unroll
    for (int c = 0; c < 16; ++c) of[dt][c] = 0.f;
  float l_lane = 0.f;

  f16x8 kf[8];
  bf16x8 vf[8];

  // prologue: K(0), V(0) for this wave's first key-block (kb = kb0 + w)
  {
    const short* kp = Kimg + (size_t)(kb0 + w) * 4096;
    const short* vp = Vimg + (size_t)(kb0 + w) * 4096;
#pragma unroll
    for (int kc = 0; kc < 8; ++kc) kf[kc] = *(const f16x8*)(kp + kc * 512 + lane * 8);
#pragma unroll
    for (int g = 0; g < 8; ++g) vf[g] = *(const bf16x8*)(vp + g * 512 + lane * 8);
  }

  for (int t = 0; t < NIT; ++t) {
    // S^T = K.Q^T (32 keys x 32 q, K=128): 8 chained MFMAs, C-layout: col=q, row=key
    f32x16 sacc;
#pragma unroll
    for (int c = 0; c < 16; ++c) sacc[c] = 0.f;
#pragma unroll
    for (int kc = 0; kc < 8; ++kc)
      sacc = __builtin_amdgcn_mfma_f32_32x32x16_f16(kf[kc], qf[kc], sacc, 0, 0, 0);

    // issue K(t+1) — kf dead after QK
    if (t + 1 < NIT) {
      const short* kp = Kimg + (size_t)(kb0 + (t + 1) * 8 + w) * 4096;
#pragma unroll
      for (int kc = 0; kc < 8; ++kc) kf[kc] = *(const f16x8*)(kp + kc * 512 + lane * 8);
    }

    // max-free softmax + in-register pack to A-frag (RNE bf16, v_perm pairs)
    u32x4 pav0, pav1;
#pragma unroll
    for (int r = 0; r < 4; ++r) {
      float pA = __builtin_amdgcn_exp2f(fmaf(sacc[2 * r], L2E, -CB));
      float pB = __builtin_amdgcn_exp2f(fmaf(sacc[2 * r + 1], L2E, -CB));
      float pC = __builtin_amdgcn_exp2f(fmaf(sacc[8 + 2 * r], L2E, -CB));
      float pD = __builtin_amdgcn_exp2f(fmaf(sacc[8 + 2 * r + 1], L2E, -CB));
      l_lane += (pA + pB) + (pC + pD);
      uint32_t uA = __builtin_bit_cast(uint32_t, pA); uA += 0x7FFFu + ((uA >> 16) & 1u);
      uint32_t uB = __builtin_bit_cast(uint32_t, pB); uB += 0x7FFFu + ((uB >> 16) & 1u);
      uint32_t uC = __builtin_bit_cast(uint32_t, pC); uC += 0x7FFFu + ((uC >> 16) & 1u);
      uint32_t uD = __builtin_bit_cast(uint32_t, pD); uD += 0x7FFFu + ((uD >> 16) & 1u);
      pav0[r] = __builtin_amdgcn_perm(uB, uA, 0x07060302u);   // [bf(pB)|bf(pA)]
      pav1[r] = __builtin_amdgcn_perm(uD, uC, 0x07060302u);
    }
    bf16x8 pa0 = __builtin_bit_cast(bf16x8, pav0);   // keys 0-15 (permuted order)
    bf16x8 pa1 = __builtin_bit_cast(bf16x8, pav1);   // keys 16-31

    // O += P.V  (V image key-permuted to match pa's key order)
#pragma unroll
    for (int dt = 0; dt < 4; ++dt) {
      of[dt] = __builtin_amdgcn_mfma_f32_32x32x16_bf16(pa0, vf[dt], of[dt], 0, 0, 0);
      of[dt] = __builtin_amdgcn_mfma_f32_32x32x16_bf16(pa1, vf[4 + dt], of[dt], 0, 0, 0);
    }

    // issue V(t+1) — vf dead after PV
    if (t + 1 < NIT) {
      const short* vp = Vimg + (size_t)(kb0 + (t + 1) * 8 + w) * 4096;
#pragma unroll
      for (int g = 0; g < 8; ++g) vf[g] = *(const bf16x8*)(vp + g * 512 + lane * 8);
    }
  }

  // combine the two half-lanes' l (each lane's q = l32 appears at half 0 and 1)
  float l_tot = l_lane + __shfl_xor(l_lane, 32);

  // ---- 8-way merge: 4 LDS regions [32 rows][132 cols] (col 128 = l), 2 rounds ----
  __syncthreads();
  float* mO = (float*)smem;
  float* R = mO + (w & 3) * 4224;
  if (w < 4) {
#pragma unroll
    for (int c = 0; c < 16; ++c) {
      const int row = (c & 3) + 8 * (c >> 2) + 4 * half;   // q-row
      float* br = R + row * 132;
#pragma unroll
      for (int dt = 0; dt < 4; ++dt) br[dt * 32 + l32] = of[dt][c];
    }
    if (half == 0) R[l32 * 132 + 128] = l_tot;
  }
  __syncthreads();
  if (w >= 4) {
#pragma unroll
    for (int c = 0; c < 16; ++c) {
      const int row = (c & 3) + 8 * (c >> 2) + 4 * half;
      float* br = R + row * 132;
#pragma unroll
      for (int dt = 0; dt < 4; ++dt) br[dt * 32 + l32] += of[dt][c];
    }
    if (half == 0) R[l32 * 132 + 128] += l_tot;
  }
  __syncthreads();
  {
    const int row = tid >> 4;            // 0..31
    const int cg = tid & 15;             // 8-col group
    float lp = mO[row * 132 + 128] + mO[4224 + row * 132 + 128] +
               mO[8448 + row * 132 + 128] + mO[12672 + row * 132 + 128];
    float4 s0 = {0.f, 0.f, 0.f, 0.f}, s1 = {0.f, 0.f, 0.f, 0.f};
#pragma unroll
    for (int rg = 0; rg < 4; ++rg) {
      const float* p = mO + rg * 4224 + row * 132 + cg * 8;
      float4 a = *(const float4*)p;
      float4 b2 = *(const float4*)(p + 4);
      s0.x += a.x; s0.y += a.y; s0.z += a.z; s0.w += a.w;
      s1.x += b2.x; s1.y += b2.y; s1.z += b2.z; s1.w += b2.w;
    }
    float* op = (kh ? Ob : Oa) + (size_t)(qrow0 + row) * DH + cg * 8;
    *(float4*)op = s0;                   // UNNORMALIZED partial
    *(float4*)(op + 4) = s1;
    if (cg == 0) (kh ? l1 : l0)[qrow0 + row] = lp;
  }
}

// ---- combine: out = (Oa + Ob) / (la + lb), 1M floats, 4/thread ----
__global__ __launch_bounds__(256) void combine_kernel(float* __restrict__ Oa,
                                                      const float* __restrict__ Ob,
                                                      const float* __restrict__ l0,
                                                      const float* __restrict__ l1) {
  const int idx = blockIdx.x * 256 + threadIdx.x;
  const int row = idx >> 5;
  const int c4 = (idx & 31) * 4;
  const float inv = 1.f / (l0[row] + l1[row]);
  float* pa = Oa + (size_t)row * DH + c4;
  const float* pb = Ob + (size_t)row * DH + c4;
  float4 a = *(const float4*)pa;
  float4 b = *(const float4*)pb;
  a.x = (a.x + b.x) * inv; a.y = (a.y + b.y) * inv;
  a.z = (a.z + b.z) * inv; a.w = (a.w + b.w) * inv;
  *(float4*)pa = a;
}

extern "C" void kernel_launch(void* const* d_in, const int* in_sizes, int n_in,
                              void* d_out, int out_size, void* d_ws, size_t ws_size,
                              hipStream_t stream) {
  const float* Q = (const float*)d_in[0];
  const float* K = (const float*)d_in[1];
  const float* V = (const float*)d_in[2];
  float* out = (float*)d_out;
  char* ws = (char*)d_ws;
  // ws layout: Kimg 2MB | Vimg 2MB | Ob 4MB | l0 32KB | l1 32KB (8.45 MB,
  // proven available in R2)
  short* Kimg = (short*)ws;
  short* Vimg = (short*)(ws + 2097152);
  float* Ob = (float*)(ws + 4194304);
  float* l0 = (float*)(ws + 8388608);
  float* l1 = l0 + SQ;
  prep_kernel<<<512, 256, 0, stream>>>(K, V, Kimg, Vimg);
  attn_split<<<512, 512, 0, stream>>>(Q, Kimg, Vimg, out, Ob, l0, l1);
  combine_kernel<<<SQ * DH / 4 / 256, 256, 0, stream>>>(out, Ob, l0, l1);
}

// Round 5
// 115.174 us; speedup vs baseline: 2.7937x; 2.7937x over previous
//
#include <hip/hip_runtime.h>
#include <hip/hip_bf16.h>
#include <stdint.h>

#define SQ 8192
#define SK 8192
#define DH 128
#define L2E 1.4426950408889634f
#define CB 40.0f             // fixed log2-domain softmax offset (R7-proven)

typedef __attribute__((ext_vector_type(8))) _Float16 f16x8;
typedef __attribute__((ext_vector_type(8))) short bf16x8;
typedef __attribute__((ext_vector_type(16))) float f32x16;
typedef __attribute__((ext_vector_type(4))) short s16x4;
typedef __attribute__((ext_vector_type(4))) unsigned int u32x4;

__device__ __forceinline__ short f2h(float f) {
  _Float16 h = (_Float16)f;
  return __builtin_bit_cast(short, h);
}
__device__ __forceinline__ short f2bf(float f) {   // RNE
  uint32_t u = __builtin_bit_cast(uint32_t, f);
  u = (u + 0x7FFFu + ((u >> 16) & 1u)) >> 16;
  return (short)u;
}

__device__ __forceinline__ void gl_lds16(const void* g, void* l) {
  __builtin_amdgcn_global_load_lds(
      (const __attribute__((address_space(1))) void*)g,
      (__attribute__((address_space(3))) void*)l, 16, 0, 0);
}

// ---- prep: blocks [0,256) build K image; blocks [256,512) build V image.
// Kimg[kb][kc][lane][j] = fp16 K[kb*32 + (lane&31)][kc*16 + (lane>>5)*8 + j]
// Vimg[kb][g=ks*4+dt][lane][j] = bf16 V[key][dt*32 + (lane&31)], key axis permuted
//   to S^T C-layout order: key = kb*32 + ks*16 + (lane>>5)*4 + (j&3) + 8*(j>>2).
__global__ __launch_bounds__(256) void prep_kernel(const float* __restrict__ K,
                                                   const float* __restrict__ V,
                                                   short* __restrict__ Kimg,
                                                   short* __restrict__ Vimg) {
  __shared__ short T[32][136];
  const int tid = threadIdx.x;
  if (blockIdx.x < 256) {
    const int kb = blockIdx.x;
#pragma unroll
    for (int i = 0; i < 2; ++i) {
      int ci = i * 256 + tid;            // chunk id, 512 per kb
      int kc = ci >> 6, lane = ci & 63;
      int key = kb * 32 + (lane & 31);
      int k0 = kc * 16 + (lane >> 5) * 8;
      const float* src = K + (size_t)key * DH + k0;
      float4 a = *(const float4*)src;
      float4 b = *(const float4*)(src + 4);
      s16x4 o0, o1;
      o0.x = f2h(a.x); o0.y = f2h(a.y); o0.z = f2h(a.z); o0.w = f2h(a.w);
      o1.x = f2h(b.x); o1.y = f2h(b.y); o1.z = f2h(b.z); o1.w = f2h(b.w);
      s16x4* dst = (s16x4*)(Kimg + (size_t)kb * 4096 + ci * 8);
      dst[0] = o0; dst[1] = o1;
    }
  } else {
    const int kb = blockIdx.x - 256;
#pragma unroll
    for (int i = 0; i < 4; ++i) {
      int fi = i * 256 + tid;            // float4 id in 32x128 tile
      int key = fi >> 5;
      int dc = (fi & 31) * 4;
      float4 v = ((const float4*)V)[(size_t)(kb * 32 + key) * (DH / 4) + (fi & 31)];
      T[key][dc + 0] = f2bf(v.x); T[key][dc + 1] = f2bf(v.y);
      T[key][dc + 2] = f2bf(v.z); T[key][dc + 3] = f2bf(v.w);
    }
    __syncthreads();
#pragma unroll
    for (int i = 0; i < 2; ++i) {
      int ci = i * 256 + tid;            // chunk id, 512 per kb
      int lane = ci & 63;
      int g = ci >> 6;                   // ks*4 + dt
      int dt = g & 3, ks = g >> 2;
      int base = ks * 16 + (lane >> 5) * 4;   // permuted key base
      int d = dt * 32 + (lane & 31);
      s16x4 o0, o1;
      o0.x = T[base + 0][d]; o0.y = T[base + 1][d];
      o0.z = T[base + 2][d]; o0.w = T[base + 3][d];
      o1.x = T[base + 8][d]; o1.y = T[base + 9][d];
      o1.z = T[base + 10][d]; o1.w = T[base + 11][d];
      s16x4* dst = (s16x4*)(Vimg + (size_t)kb * 4096 + ci * 8);
      dst[0] = o0; dst[1] = o1;
    }
  }
}

// ======================= MAIN PATH: q=128, 4-way key split, T4 pipeline ======
// Grid 256 = 64 qb x 4 kh (kh = b&3 pins key quarter per XCD). Block: 8 waves =
// qh(0..3) x kw(0..1). Per iter (64 keys = 2 kb): 32 KB staged (K 16 + V 16)
// into TRIPLE-buffered LDS; each staged byte read by 4 qh waves (4x register
// reuse -> global delivery 32 KB/CU-iter). Counted-vmcnt schedule (T4): STAGE
// for iter t+2 issued in iter t; barrier waits vmcnt(4) -> newest 4 loads stay
// in flight across the barrier, older STAGE(t+1) proven landed (vmcnt retires
// oldest-first). No vmcnt(0) drain in the loop. Max-free softmax (fixed CB)
// makes key-quarter partials additive: block writes unnormalized O + l.
#define NIT4 32              // 2048 keys / 64 per iter
__global__ __launch_bounds__(512, 2) void attn_q128(const float* __restrict__ Q,
                                                    const short* __restrict__ Kimg,
                                                    const short* __restrict__ Vimg,
                                                    float* __restrict__ Opart,
                                                    float* __restrict__ lpart) {
  // 3 stage buffers x 32 KB = 96 KB; merge region (67584 B) aliases after loop
  __shared__ __align__(16) char smem[98304];
  short* stg = (short*)smem;
  const int tid = threadIdx.x;
  const int w = tid >> 6;
  const int lane = tid & 63;
  const int half = lane >> 5;
  const int l32 = lane & 31;
  const int qh = w >> 1;               // q-subtile 0..3
  const int kw = w & 1;                // key half of the 64-key tile
  const int b = blockIdx.x;
  const int kh = b & 3;                // key quarter (XCD-pinned: xcd = b&7)
  const int qb = b >> 2;               // 0..63
  const int qrow0 = qb * 128 + qh * 32;
  const int kb0 = kh * 64;             // first 32-key block of this quarter

  // Q B-frags fp16: qf[kc][j] = Q[qrow0 + l32][kc*16 + half*8 + j]
  f16x8 qf[8];
  {
    const float* qp = Q + (size_t)(qrow0 + l32) * DH + half * 8;
#pragma unroll
    for (int kc = 0; kc < 8; ++kc) {
      float4 a = *(const float4*)(qp + kc * 16);
      float4 b2 = *(const float4*)(qp + kc * 16 + 4);
      f16x8 h;
      h[0] = (_Float16)a.x; h[1] = (_Float16)a.y; h[2] = (_Float16)a.z; h[3] = (_Float16)a.w;
      h[4] = (_Float16)b2.x; h[5] = (_Float16)b2.y; h[6] = (_Float16)b2.z; h[7] = (_Float16)b2.w;
      qf[kc] = h;
    }
  }

  f32x16 of[4];
#pragma unroll
  for (int dt = 0; dt < 4; ++dt)
#pragma unroll
    for (int c = 0; c < 16; ++c) of[dt][c] = 0.f;
  float l_lane = 0.f;

  // staging roles: waves 0-3 stage K (4 KB each), waves 4-7 stage V (4 KB each).
  // Tile t = kbs {kb0+2t, kb0+2t+1}: 16 KB contiguous in each image.
  const short* gsrc = (w < 4 ? Kimg : Vimg) + (size_t)kb0 * 4096 + (w & 3) * 2048 + lane * 8;
  const int ldso = ((w < 4) ? 0 : 8192) + (w & 3) * 2048;

  auto STAGE = [&](int c, int t) {
    const short* g = gsrc + (size_t)t * 8192;    // 2 kb * 4096 shorts per iter
    short* l = stg + c * 16384 + ldso;
#pragma unroll
    for (int j = 0; j < 4; ++j)
      gl_lds16(g + j * 512, l + j * 512);        // 64 lanes x 16 B = 1 KB per call
  };

  // prologue: fill buffers 0 and 1; enter loop with STAGE(0) landed,
  // STAGE(1)'s 4 loads allowed to remain in flight.
  STAGE(0, 0);
  STAGE(1, 1);
  asm volatile("s_waitcnt vmcnt(4)" ::: "memory");
  __builtin_amdgcn_s_barrier();
  __builtin_amdgcn_sched_barrier(0);

  for (int t = 0; t < NIT4; ++t) {
    const int cur = t % 3;
    // K frags for this wave's kb (= kb0 + 2t + kw) from LDS
    const short* bk = stg + cur * 16384 + kw * 4096 + lane * 8;
    f16x8 kf[8];
#pragma unroll
    for (int kc = 0; kc < 8; ++kc) kf[kc] = *(const f16x8*)(bk + kc * 512);

    // issue staging for iter t+2 (deep prefetch; lands before its barrier)
    if (t + 2 < NIT4) STAGE((t + 2) % 3, t + 2);

    // S^T = K.Q^T (32 keys x 32 q, K=128): 8 chained MFMAs, C: col=q, row=key
    f32x16 sacc;
#pragma unroll
    for (int c = 0; c < 16; ++c) sacc[c] = 0.f;
#pragma unroll
    for (int kc = 0; kc < 8; ++kc)
      sacc = __builtin_amdgcn_mfma_f32_32x32x16_f16(kf[kc], qf[kc], sacc, 0, 0, 0);

    // V frags (independent of sacc -> overlaps softmax)
    const short* bv = stg + cur * 16384 + 8192 + kw * 4096 + lane * 8;
    bf16x8 vf[8];
#pragma unroll
    for (int g2 = 0; g2 < 8; ++g2) vf[g2] = *(const bf16x8*)(bv + g2 * 512);

    // max-free softmax + in-register pack to A-frag (RNE bf16, v_perm pairs)
    u32x4 pav0, pav1;
#pragma unroll
    for (int r = 0; r < 4; ++r) {
      float pA = __builtin_amdgcn_exp2f(fmaf(sacc[2 * r], L2E, -CB));
      float pB = __builtin_amdgcn_exp2f(fmaf(sacc[2 * r + 1], L2E, -CB));
      float pC = __builtin_amdgcn_exp2f(fmaf(sacc[8 + 2 * r], L2E, -CB));
      float pD = __builtin_amdgcn_exp2f(fmaf(sacc[8 + 2 * r + 1], L2E, -CB));
      l_lane += (pA + pB) + (pC + pD);
      uint32_t uA = __builtin_bit_cast(uint32_t, pA); uA += 0x7FFFu + ((uA >> 16) & 1u);
      uint32_t uB = __builtin_bit_cast(uint32_t, pB); uB += 0x7FFFu + ((uB >> 16) & 1u);
      uint32_t uC = __builtin_bit_cast(uint32_t, pC); uC += 0x7FFFu + ((uC >> 16) & 1u);
      uint32_t uD = __builtin_bit_cast(uint32_t, pD); uD += 0x7FFFu + ((uD >> 16) & 1u);
      pav0[r] = __builtin_amdgcn_perm(uB, uA, 0x07060302u);   // [bf(pB)|bf(pA)]
      pav1[r] = __builtin_amdgcn_perm(uD, uC, 0x07060302u);
    }
    bf16x8 pa0 = __builtin_bit_cast(bf16x8, pav0);   // keys 0-15 (permuted order)
    bf16x8 pa1 = __builtin_bit_cast(bf16x8, pav1);   // keys 16-31

    // O += P.V  (V image key-permuted to match pa's key order)
#pragma unroll
    for (int dt = 0; dt < 4; ++dt) {
      of[dt] = __builtin_amdgcn_mfma_f32_32x32x16_bf16(pa0, vf[dt], of[dt], 0, 0, 0);
      of[dt] = __builtin_amdgcn_mfma_f32_32x32x16_bf16(pa1, vf[4 + dt], of[dt], 0, 0, 0);
    }

    // T4 barrier: newest 4 loads (STAGE(t+2)) may stay in flight; STAGE(t+1)
    // (older) is guaranteed landed when vmcnt <= 4. Never drain to 0 in-loop.
    if (t + 1 < NIT4) {
      asm volatile("s_waitcnt vmcnt(4)" ::: "memory");
      __builtin_amdgcn_s_barrier();
      __builtin_amdgcn_sched_barrier(0);
    }
  }

  // combine the two half-lanes' l (each lane's q = l32 appears at half 0 and 1)
  float l_tot = l_lane + __shfl_xor(l_lane, 32);

  // ---- kw-pair merge per qh: 4 LDS regions [32 rows][132 cols] (col 128=l) ----
  __syncthreads();
  float* mO = (float*)smem;
  float* R = mO + qh * 4224;
  if (kw == 0) {
#pragma unroll
    for (int c = 0; c < 16; ++c) {
      const int row = (c & 3) + 8 * (c >> 2) + 4 * half;   // q-row within 32
      float* br = R + row * 132;
#pragma unroll
      for (int dt = 0; dt < 4; ++dt) br[dt * 32 + l32] = of[dt][c];
    }
    if (half == 0) R[l32 * 132 + 128] = l_tot;
  }
  __syncthreads();
  if (kw == 1) {
#pragma unroll
    for (int c = 0; c < 16; ++c) {
      const int row = (c & 3) + 8 * (c >> 2) + 4 * half;
      float* br = R + row * 132;
#pragma unroll
      for (int dt = 0; dt < 4; ++dt) br[dt * 32 + l32] += of[dt][c];
    }
    if (half == 0) R[l32 * 132 + 128] += l_tot;
  }
  __syncthreads();
  {
    const int row = tid >> 2;            // 0..127
    const int cg = tid & 3;              // 32-col group
    const float* p = mO + (row >> 5) * 4224 + (row & 31) * 132;
    float* dst = Opart + ((size_t)kh << 20) + (size_t)(qb * 128 + row) * DH + cg * 32;
#pragma unroll
    for (int k = 0; k < 8; ++k)
      ((float4*)dst)[k] = ((const float4*)(p + cg * 32))[k];   // UNNORMALIZED
    if (cg == 0) lpart[kh * SQ + qb * 128 + row] = p[128];
  }
}

// ---- combine4: out = sum4(Oi) / sum4(li) ----
__global__ __launch_bounds__(256) void combine4(const float* __restrict__ Opart,
                                                const float* __restrict__ lpart,
                                                float* __restrict__ out) {
  const int idx = blockIdx.x * 256 + threadIdx.x;
  const int row = idx >> 5;
  const int c4 = (idx & 31) * 4;
  const float inv = 1.f / (lpart[row] + lpart[SQ + row] +
                           lpart[2 * SQ + row] + lpart[3 * SQ + row]);
  const size_t off = (size_t)row * DH + c4;
  float4 a = *(const float4*)(Opart + off);
  const float4 b = *(const float4*)(Opart + (1u << 20) + off);
  const float4 c = *(const float4*)(Opart + (2u << 20) + off);
  const float4 d = *(const float4*)(Opart + (3u << 20) + off);
  a.x = (a.x + b.x + c.x + d.x) * inv;
  a.y = (a.y + b.y + c.y + d.y) * inv;
  a.z = (a.z + b.z + c.z + d.z) * inv;
  a.w = (a.w + b.w + c.w + d.w) * inv;
  *(float4*)(out + off) = a;
}

// ======================= FALLBACK (R2-proven, 50.5 us attn) ==================
__global__ __launch_bounds__(512, 2) void attn_fb(const float* __restrict__ Q,
                                                  const short* __restrict__ Kimg,
                                                  const short* __restrict__ Vimg,
                                                  float* __restrict__ Oa,
                                                  float* __restrict__ Ob,
                                                  float* __restrict__ l0,
                                                  float* __restrict__ l1) {
  __shared__ __align__(16) char smem[131072];
  short* stg = (short*)smem;
  const int tid = threadIdx.x;
  const int w = tid >> 6;
  const int lane = tid & 63;
  const int half = lane >> 5;
  const int l32 = lane & 31;
  const int qh = w >> 2;
  const int ks = w & 3;
  const int qb = blockIdx.x >> 1;
  const int kh = blockIdx.x & 1;
  const int qrow0 = qb * 64 + qh * 32;
  const int kb0 = kh * 128;

  f16x8 qf[8];
  {
    const float* qp = Q + (size_t)(qrow0 + l32) * DH + half * 8;
#pragma unroll
    for (int kc = 0; kc < 8; ++kc) {
      float4 a = *(const float4*)(qp + kc * 16);
      float4 b = *(const float4*)(qp + kc * 16 + 4);
      f16x8 h;
      h[0] = (_Float16)a.x; h[1] = (_Float16)a.y; h[2] = (_Float16)a.z; h[3] = (_Float16)a.w;
      h[4] = (_Float16)b.x; h[5] = (_Float16)b.y; h[6] = (_Float16)b.z; h[7] = (_Float16)b.w;
      qf[kc] = h;
    }
  }

  f32x16 of[4];
#pragma unroll
  for (int dt = 0; dt < 4; ++dt)
#pragma unroll
    for (int c = 0; c < 16; ++c) of[dt][c] = 0.f;
  float l_lane = 0.f;

  const short* gsrc = (w < 4 ? Kimg : Vimg) + ((size_t)kb0 + ks) * 4096 + lane * 8;
  short* lbase = stg + ((w >= 4) ? 16384 : 0) + ks * 4096;

  auto STAGE = [&](int c, int t) {
    const short* g = gsrc + (size_t)t * 4 * 4096;
    short* l = lbase + c * 32768;
#pragma unroll
    for (int j = 0; j < 8; ++j)
      gl_lds16(g + j * 512, l + j * 512);
  };

  STAGE(0, 0);
  __syncthreads();
  int cur = 0;

  for (int t = 0; t < 32; ++t) {
    const short* bk = stg + cur * 16384 * 2 + ks * 4096 + lane * 8;
    f16x8 kf[8];
#pragma unroll
    for (int kc = 0; kc < 8; ++kc) kf[kc] = *(const f16x8*)(bk + kc * 512);

    if (t + 1 < 32) STAGE(cur ^ 1, t + 1);

    f32x16 sacc;
#pragma unroll
    for (int c = 0; c < 16; ++c) sacc[c] = 0.f;
#pragma unroll
    for (int kc = 0; kc < 8; ++kc)
      sacc = __builtin_amdgcn_mfma_f32_32x32x16_f16(kf[kc], qf[kc], sacc, 0, 0, 0);

    const short* bv = stg + cur * 16384 * 2 + 16384 + ks * 4096 + lane * 8;
    bf16x8 vf[8];
#pragma unroll
    for (int g2 = 0; g2 < 8; ++g2) vf[g2] = *(const bf16x8*)(bv + g2 * 512);

    u32x4 pav0, pav1;
#pragma unroll
    for (int r = 0; r < 4; ++r) {
      float pA = __builtin_amdgcn_exp2f(fmaf(sacc[2 * r], L2E, -CB));
      float pB = __builtin_amdgcn_exp2f(fmaf(sacc[2 * r + 1], L2E, -CB));
      float pC = __builtin_amdgcn_exp2f(fmaf(sacc[8 + 2 * r], L2E, -CB));
      float pD = __builtin_amdgcn_exp2f(fmaf(sacc[8 + 2 * r + 1], L2E, -CB));
      l_lane += (pA + pB) + (pC + pD);
      uint32_t uA = __builtin_bit_cast(uint32_t, pA); uA += 0x7FFFu + ((uA >> 16) & 1u);
      uint32_t uB = __builtin_bit_cast(uint32_t, pB); uB += 0x7FFFu + ((uB >> 16) & 1u);
      uint32_t uC = __builtin_bit_cast(uint32_t, pC); uC += 0x7FFFu + ((uC >> 16) & 1u);
      uint32_t uD = __builtin_bit_cast(uint32_t, pD); uD += 0x7FFFu + ((uD >> 16) & 1u);
      pav0[r] = __builtin_amdgcn_perm(uB, uA, 0x07060302u);
      pav1[r] = __builtin_amdgcn_perm(uD, uC, 0x07060302u);
    }
    bf16x8 pa0 = __builtin_bit_cast(bf16x8, pav0);
    bf16x8 pa1 = __builtin_bit_cast(bf16x8, pav1);

#pragma unroll
    for (int dt = 0; dt < 4; ++dt) {
      of[dt] = __builtin_amdgcn_mfma_f32_32x32x16_bf16(pa0, vf[dt], of[dt], 0, 0, 0);
      of[dt] = __builtin_amdgcn_mfma_f32_32x32x16_bf16(pa1, vf[4 + dt], of[dt], 0, 0, 0);
    }

    __syncthreads();
    cur ^= 1;
  }

  float l_tot = l_lane + __shfl_xor(l_lane, 32);

  __syncthreads();
  float* mO = (float*)smem;
  float* R = mO + (qh * 2 + (ks & 1)) * 4224;
  if (ks < 2) {
#pragma unroll
    for (int c = 0; c < 16; ++c) {
      const int row = (c & 3) + 8 * (c >> 2) + 4 * half;
      float* br = R + row * 132;
#pragma unroll
      for (int dt = 0; dt < 4; ++dt) br[dt * 32 + l32] = of[dt][c];
    }
    if (half == 0) R[l32 * 132 + 128] = l_tot;
  }
  __syncthreads();
  if (ks >= 2) {
#pragma unroll
    for (int c = 0; c < 16; ++c) {
      const int row = (c & 3) + 8 * (c >> 2) + 4 * half;
      float* br = R + row * 132;
#pragma unroll
      for (int dt = 0; dt < 4; ++dt) br[dt * 32 + l32] += of[dt][c];
    }
    if (half == 0) R[l32 * 132 + 128] += l_tot;
  }
  __syncthreads();
  {
    const int row = tid >> 3;
    const int cg = tid & 7;
    const int qh2 = row >> 5;
    const int r32 = row & 31;
    const float* Ra = mO + (qh2 * 2 + 0) * 4224 + r32 * 132;
    const float* Rb = mO + (qh2 * 2 + 1) * 4224 + r32 * 132;
    float lp = Ra[128] + Rb[128];
    float* dst = (kh ? Ob : Oa) + (size_t)(qb * 64 + row) * DH + cg * 16;
#pragma unroll
    for (int k = 0; k < 4; ++k) {
      float4 a = *(const float4*)(Ra + cg * 16 + k * 4);
      float4 b = *(const float4*)(Rb + cg * 16 + k * 4);
      a.x += b.x; a.y += b.y; a.z += b.z; a.w += b.w;
      *(float4*)(dst + k * 4) = a;
    }
    if (cg == 0) (kh ? l1 : l0)[qb * 64 + row] = lp;
  }
}

__global__ __launch_bounds__(256) void combine2(float* __restrict__ Oa,
                                                const float* __restrict__ Ob,
                                                const float* __restrict__ l0,
                                                const float* __restrict__ l1) {
  const int idx = blockIdx.x * 256 + threadIdx.x;
  const int row = idx >> 5;
  const int c4 = (idx & 31) * 4;
  const float inv = 1.f / (l0[row] + l1[row]);
  float* pa = Oa + (size_t)row * DH + c4;
  const float* pb = Ob + (size_t)row * DH + c4;
  float4 a = *(const float4*)pa;
  float4 b = *(const float4*)pb;
  a.x = (a.x + b.x) * inv; a.y = (a.y + b.y) * inv;
  a.z = (a.z + b.z) * inv; a.w = (a.w + b.w) * inv;
  *(float4*)pa = a;
}

extern "C" void kernel_launch(void* const* d_in, const int* in_sizes, int n_in,
                              void* d_out, int out_size, void* d_ws, size_t ws_size,
                              hipStream_t stream) {
  const float* Q = (const float*)d_in[0];
  const float* K = (const float*)d_in[1];
  const float* V = (const float*)d_in[2];
  float* out = (float*)d_out;
  char* ws = (char*)d_ws;
  short* Kimg = (short*)ws;
  short* Vimg = (short*)(ws + 2097152);
  prep_kernel<<<512, 256, 0, stream>>>(K, V, Kimg, Vimg);
  // main path: Kimg 2MB | Vimg 2MB | Opart 16MB | lpart 128KB = 21102592 B
  if (ws_size >= (size_t)21102592) {
    float* Opart = (float*)(ws + 4194304);
    float* lpart = (float*)(ws + 20971520);
    attn_q128<<<256, 512, 0, stream>>>(Q, Kimg, Vimg, Opart, lpart);
    combine4<<<SQ * DH / 4 / 256, 256, 0, stream>>>(Opart, lpart, out);
  } else {  // R2-proven fallback: Kimg | Vimg | Ob 4MB | l0 | l1 (8.45 MB)
    float* Ob = (float*)(ws + 4194304);
    float* l0 = (float*)(ws + 8388608);
    float* l1 = l0 + SQ;
    attn_fb<<<SQ / 64 * 2, 512, 0, stream>>>(Q, Kimg, Vimg, out, Ob, l0, l1);
    combine2<<<SQ * DH / 4 / 256, 256, 0, stream>>>(out, Ob, l0, l1);
  }
}